// Round 2
// baseline (111.998 us; speedup 1.0000x reference)
//
#include <hip/hip_runtime.h>
#include <cstring>
#include <cstdint>
#include <cmath>

// ---------------------------------------------------------------------------
// Threefry-2x32 (20 rounds) — exact JAX PRNG
// ---------------------------------------------------------------------------
__host__ __device__ static inline void tf2x32(uint32_t k0, uint32_t k1,
                                              uint32_t& x0, uint32_t& x1) {
    uint32_t ks2 = k0 ^ k1 ^ 0x1BD11BDAu;
    x0 += k0; x1 += k1;
#define TFR(r) { x0 += x1; x1 = (x1 << r) | (x1 >> (32 - r)); x1 ^= x0; }
    TFR(13) TFR(15) TFR(26) TFR(6)
    x0 += k1;  x1 += ks2 + 1u;
    TFR(17) TFR(29) TFR(16) TFR(24)
    x0 += ks2; x1 += k0 + 2u;
    TFR(13) TFR(15) TFR(26) TFR(6)
    x0 += k0;  x1 += k1 + 3u;
    TFR(17) TFR(29) TFR(16) TFR(24)
    x0 += k1;  x1 += ks2 + 4u;
    TFR(13) TFR(15) TFR(26) TFR(6)
    x0 += ks2; x1 += k0 + 5u;
#undef TFR
}

// Partitionable-mode 32-bit random bits for flat index i (< 2^32):
// counter = (hi=0, lo=i); bits = out0 ^ out1
__host__ __device__ static inline uint32_t pbits(uint32_t k0, uint32_t k1, uint32_t i) {
    uint32_t a = 0u, b = i;
    tf2x32(k0, k1, a, b);
    return a ^ b;
}

// bits -> uniform [0,1) exactly as jax: bitcast(bits>>9 | 0x3f800000) - 1
__host__ __device__ static inline float bits_to_u01(uint32_t bits) {
    uint32_t u = (bits >> 9) | 0x3f800000u;
    float f; memcpy(&f, &u, 4);
    return f - 1.0f;
}

// XLA ErfInv (Giles 2010, float32)
__host__ __device__ static inline float erfinv_f(float x) {
    float w = -log1pf(-x * x);
    float p;
    if (w < 5.0f) {
        w = w - 2.5f;
        p = 2.81022636e-08f;
        p = fmaf(p, w, 3.43273939e-07f);
        p = fmaf(p, w, -3.5233877e-06f);
        p = fmaf(p, w, -4.39150654e-06f);
        p = fmaf(p, w, 0.00021858087f);
        p = fmaf(p, w, -0.00125372503f);
        p = fmaf(p, w, -0.00417768164f);
        p = fmaf(p, w, 0.246640727f);
        p = fmaf(p, w, 1.50140941f);
    } else {
        w = sqrtf(w) - 3.0f;
        p = -0.000200214257f;
        p = fmaf(p, w, 0.000100950558f);
        p = fmaf(p, w, 0.00134934322f);
        p = fmaf(p, w, -0.00367342844f);
        p = fmaf(p, w, 0.00573950773f);
        p = fmaf(p, w, -0.0076224613f);
        p = fmaf(p, w, 0.00943887047f);
        p = fmaf(p, w, 1.00167406f);
        p = fmaf(p, w, 2.83297682f);
    }
    return p * x;
}

// jax.random.normal float32: lo = -1+2^-24; u = max(lo, u01*2 + lo); sqrt2*erfinv(u)
__host__ __device__ static inline float normal_from_bits(uint32_t bits) {
    const float LO = -0.999999940395355224609375f;  // -1 + 2^-24
    float u01 = bits_to_u01(bits);
    float u = u01 * 2.0f + LO;   // (hi-lo) rounds to exactly 2.0f in f32
    u = (u > LO) ? u : LO;
    return 1.4142135623730951f * erfinv_f(u);
}

// ---------------------------------------------------------------------------
// Host-side float32 4x4 matrix helpers (mirror reference composition order)
// ---------------------------------------------------------------------------
struct M4 { float m[4][4]; };

static M4 m4_eye() {
    M4 r;
    for (int i = 0; i < 4; ++i)
        for (int j = 0; j < 4; ++j) r.m[i][j] = (i == j) ? 1.0f : 0.0f;
    return r;
}
static M4 m4_mul(const M4& A, const M4& B) {  // A @ B, f32 accumulate
    M4 r;
    for (int i = 0; i < 4; ++i)
        for (int j = 0; j < 4; ++j) {
            float s = 0.0f;
            for (int k = 0; k < 4; ++k) s += A.m[i][k] * B.m[k][j];
            r.m[i][j] = s;
        }
    return r;
}
static M4 m4_scale(float sx, float sy, float sz) {
    M4 r = m4_eye(); r.m[0][0] = sx; r.m[1][1] = sy; r.m[2][2] = sz; return r;
}
static M4 m4_trans(float tx, float ty, float tz) {
    M4 r = m4_eye(); r.m[0][3] = tx; r.m[1][3] = ty; r.m[2][3] = tz; return r;
}
static M4 m4_rotz(float th) {
    float c = cosf(th), s = sinf(th);
    M4 r = m4_eye();
    r.m[0][0] = c; r.m[0][1] = -s; r.m[1][0] = s; r.m[1][1] = c;
    return r;
}
static M4 m4_rotluma(float th) {
    const float a  = 0.57735026918962576f;  // f32(1/sqrt(3))
    const float a2 = 1.0f / 3.0f;           // f32(1/3)
    float c = cosf(th), s = sinf(th), cc = 1.0f - c;
    float d  = a2 * cc + c;
    float mm = a2 * cc - a * s;
    float pp = a2 * cc + a * s;
    M4 r = m4_eye();
    r.m[0][0] = d;  r.m[0][1] = mm; r.m[0][2] = pp;
    r.m[1][0] = pp; r.m[1][1] = d;  r.m[1][2] = mm;
    r.m[2][0] = mm; r.m[2][1] = pp; r.m[2][2] = d;
    return r;
}

// ---------------------------------------------------------------------------
// Per-batch parameters passed by value (kernarg, ~1.8 KB)
// ---------------------------------------------------------------------------
struct AugParams {
    float G[16][12];   // rows 0..2 of inverse geometric transform (3x4)
    float C[16][12];   // rows 0..2 of color matrix (3x3 + translation col)
    float sigma[16];
    float cx[16], cy[16], cz[16];
    uint32_t nk0, nk1; // noise-field key
};

static void build_params(AugParams& P) {
    // subkeys: split(key(42), 24) — partitionable (foldlike):
    // key j = (out0, out1) of threefry(key, (0, j))
    uint32_t sk0[24], sk1[24];
    for (int j = 0; j < 24; ++j) {
        uint32_t a = 0u, b = (uint32_t)j;
        tf2x32(0u, 42u, a, b);
        sk0[j] = a; sk1[j] = b;
    }

    float u_xf[16], u_r90[16], u_ti[48], n_sc[16], u_r1[16], n_an[16], u_r2[16];
    float n_tf[48], n_br[16], n_ct[16], u_lf[16], u_hue[16], n_sat[16], n_sig[16], u_cut[48];

    auto fill_u = [&](int j, int n, float* o) {
        for (int i = 0; i < n; ++i) o[i] = bits_to_u01(pbits(sk0[j], sk1[j], (uint32_t)i));
    };
    auto fill_n = [&](int j, int n, float* o) {
        for (int i = 0; i < n; ++i) o[i] = normal_from_bits(pbits(sk0[j], sk1[j], (uint32_t)i));
    };

    fill_u(0, 16, u_xf);  fill_u(1, 16, u_r90);  fill_u(2, 48, u_ti);
    fill_n(3, 16, n_sc);  fill_u(4, 16, u_r1);   fill_n(5, 16, n_an);
    fill_u(6, 16, u_r2);  fill_n(7, 48, n_tf);   fill_n(8, 16, n_br);
    fill_n(9, 16, n_ct);  fill_u(10, 16, u_lf);  fill_u(11, 16, u_hue);
    fill_n(12, 16, n_sat); fill_n(13, 16, n_sig); fill_u(15, 48, u_cut);
    P.nk0 = sk0[14]; P.nk1 = sk1[14];  // key 14 -> noise field

    const float PI_F = 3.14159265358979323846f;      // rounds to f32(pi)
    const float HPI_F = 1.5707963267948966f;         // rounds to f32(pi/2)

    for (int b = 0; b < 16; ++b) {
        // ---- geometric (right-multiplied inverse transform) ----
        M4 G = m4_eye();
        float i1 = floorf(u_xf[b] * 2.0f);                       // xflip
        G = m4_mul(G, m4_scale(1.0f - 2.0f * i1, 1.0f, 1.0f));
        float i2 = floorf(u_r90[b] * 4.0f);                      // rot90 z
        G = m4_mul(G, m4_rotz(-HPI_F * i2));
        float t0 = (u_ti[3 * b + 0] * 2.0f - 1.0f) * 0.125f;     // int translate
        float t1 = (u_ti[3 * b + 1] * 2.0f - 1.0f) * 0.125f;
        float t2 = (u_ti[3 * b + 2] * 2.0f - 1.0f) * 0.125f;
        G = m4_mul(G, m4_trans(-rintf(t0 * 64.0f), -rintf(t1 * 64.0f), -rintf(t2 * 64.0f)));
        float s = exp2f(n_sc[b] * 0.2f);                         // iso scale
        G = m4_mul(G, m4_scale(1.0f / s, 1.0f / s, 1.0f / s));
        float th1 = (u_r1[b] * 2.0f - 1.0f) * PI_F;              // pre-rot
        G = m4_mul(G, m4_rotz(-th1));
        float s2 = exp2f(n_an[b] * 0.2f);                        // aniso
        G = m4_mul(G, m4_scale(1.0f / s2, s2, 1.0f));
        float th2 = (u_r2[b] * 2.0f - 1.0f) * PI_F;              // post-rot
        G = m4_mul(G, m4_rotz(-th2));
        float f0 = n_tf[3 * b + 0] * 0.125f;                     // frac translate
        float f1 = n_tf[3 * b + 1] * 0.125f;
        float f2 = n_tf[3 * b + 2] * 0.125f;
        G = m4_mul(G, m4_trans(-f0 * 64.0f, -f1 * 64.0f, -f2 * 64.0f));

        // ---- color (left-multiplied) ----
        M4 C = m4_eye();
        float br = n_br[b] * 0.2f;                               // brightness
        C = m4_mul(m4_trans(br, br, br), C);
        float ct = exp2f(n_ct[b] * 0.5f);                        // contrast
        C = m4_mul(m4_scale(ct, ct, ct), C);
        const float va = 0.57735026918962576f;
        float v4[4] = { va, va, va, 0.0f };
        float ilf = floorf(u_lf[b] * 2.0f);                      // lumaflip
        M4 L;
        for (int r = 0; r < 4; ++r)
            for (int c = 0; c < 4; ++c)
                L.m[r][c] = ((r == c) ? 1.0f : 0.0f) - 2.0f * (v4[r] * v4[c]) * ilf;
        C = m4_mul(L, C);
        float thh = (u_hue[b] * 2.0f - 1.0f) * PI_F;             // hue
        C = m4_mul(m4_rotluma(thh), C);
        float ss = exp2f(n_sat[b] * 1.0f);                       // saturation
        M4 S;
        for (int r = 0; r < 4; ++r)
            for (int c = 0; c < 4; ++c) {
                float vv = v4[r] * v4[c];
                S.m[r][c] = vv + (((r == c) ? 1.0f : 0.0f) - vv) * ss;
            }
        C = m4_mul(S, C);

        P.sigma[b] = fabsf(n_sig[b]) * 0.1f;
        P.cx[b] = u_cut[3 * b + 0];
        P.cy[b] = u_cut[3 * b + 1];
        P.cz[b] = u_cut[3 * b + 2];
        for (int r = 0; r < 3; ++r)
            for (int c = 0; c < 4; ++c) {
                P.G[b][r * 4 + c] = G.m[r][c];
                P.C[b][r * 4 + c] = C.m[r][c];
            }
    }
}

// ---------------------------------------------------------------------------
// Fused augment kernel: warp + color + noise + cutout
// one thread per (b, z, y, x); handles all 3 channels
// ---------------------------------------------------------------------------
__global__ __launch_bounds__(256) void aug_kernel(const float* __restrict__ in,
                                                  float* __restrict__ out,
                                                  AugParams P) {
    const int bid = blockIdx.x;
    const int b = bid >> 10;                              // 1024 blocks per batch
    const int vox = ((bid & 1023) << 8) | threadIdx.x;    // 0..262143
    const int x = vox & 63;
    const int y = (vox >> 6) & 63;
    const int z = vox >> 12;

    const float* Gb = P.G[b];
    const float hx = (float)x - 31.5f;
    const float hy = (float)y - 31.5f;
    const float hz = (float)z - 31.5f;
    float sx = Gb[0] * hx + Gb[1] * hy + Gb[2]  * hz + Gb[3]  + 31.5f;
    float sy = Gb[4] * hx + Gb[5] * hy + Gb[6]  * hz + Gb[7]  + 31.5f;
    float sz = Gb[8] * hx + Gb[9] * hy + Gb[10] * hz + Gb[11] + 31.5f;

    float fx0 = floorf(sx), fy0 = floorf(sy), fz0 = floorf(sz);
    float wx = sx - fx0, wy = sy - fy0, wz = sz - fz0;
    int ix0 = (int)fx0, iy0 = (int)fy0, iz0 = (int)fz0;

    const float* imb = in + (size_t)b * 786432;
    float r = 0.0f, g = 0.0f, bl = 0.0f;

#pragma unroll
    for (int dz = 0; dz < 2; ++dz) {
        int iz = iz0 + dz;
        bool vz = (iz >= 0) && (iz < 64);
        int izc = iz < 0 ? 0 : (iz > 63 ? 63 : iz);
        float wzf = dz ? wz : (1.0f - wz);
#pragma unroll
        for (int dy = 0; dy < 2; ++dy) {
            int iy = iy0 + dy;
            bool vy = (iy >= 0) && (iy < 64);
            int iyc = iy < 0 ? 0 : (iy > 63 ? 63 : iy);
            float wyf = dy ? wy : (1.0f - wy);
            float wzy = wzf * wyf;
#pragma unroll
            for (int dx = 0; dx < 2; ++dx) {
                int ix = ix0 + dx;
                bool vx = (ix >= 0) && (ix < 64);
                int ixc = ix < 0 ? 0 : (ix > 63 ? 63 : ix);
                float wxf = dx ? wx : (1.0f - wx);
                float w = wzy * wxf;
                bool v = vz && vy && vx;
                int off = (izc << 12) | (iyc << 6) | ixc;
                float vr = v ? imb[off]           : 0.0f;
                float vg = v ? imb[262144 + off]  : 0.0f;
                float vb = v ? imb[524288 + off]  : 0.0f;
                r  = fmaf(vr, w, r);
                g  = fmaf(vg, w, g);
                bl = fmaf(vb, w, bl);
            }
        }
    }

    // color transform
    const float* Cb = P.C[b];
    float o0 = Cb[0] * r + Cb[1] * g + Cb[2]  * bl + Cb[3];
    float o1 = Cb[4] * r + Cb[5] * g + Cb[6]  * bl + Cb[7];
    float o2 = Cb[8] * r + Cb[9] * g + Cb[10] * bl + Cb[11];

    // noise (partitionable: bits = out0^out1 of threefry(key14, (0, flat)))
    const uint32_t l0 = (uint32_t)b * 786432u + (uint32_t)vox;
    const float sg = P.sigma[b];
    o0 += normal_from_bits(pbits(P.nk0, P.nk1, l0))            * sg;
    o1 += normal_from_bits(pbits(P.nk0, P.nk1, l0 + 262144u))  * sg;
    o2 += normal_from_bits(pbits(P.nk0, P.nk1, l0 + 524288u))  * sg;

    // cutout (bit-exact comparisons: all operands exact f32)
    float fxn = ((float)x + 0.5f) / 64.0f;
    float fyn = ((float)y + 0.5f) / 64.0f;
    float fzn = ((float)z + 0.5f) / 64.0f;
    bool keep = (fabsf(fxn - P.cx[b]) >= 0.25f) ||
                (fabsf(fyn - P.cy[b]) >= 0.25f) ||
                (fabsf(fzn - P.cz[b]) >= 0.25f);
    float mk = keep ? 1.0f : 0.0f;

    size_t ob = (size_t)b * 786432 + (size_t)vox;
    out[ob]           = o0 * mk;
    out[ob + 262144]  = o1 * mk;
    out[ob + 524288]  = o2 * mk;
}

// ---------------------------------------------------------------------------
extern "C" void kernel_launch(void* const* d_in, const int* in_sizes, int n_in,
                              void* d_out, int out_size, void* d_ws, size_t ws_size,
                              hipStream_t stream) {
    const float* in = (const float*)d_in[0];
    float* out = (float*)d_out;

    AugParams P;
    build_params(P);  // pure host math, deterministic, graph-capture safe

    dim3 grid(16 * 1024), block(256);
    aug_kernel<<<grid, block, 0, stream>>>(in, out, P);
}